// Round 5
// baseline (854953.613 us; speedup 1.0000x reference)
//
#include <hip/hip_runtime.h>
#include <hip/hip_fp16.h>

#define T_LEN 131072
#define HID 256
#define G3 768   // 3*HID

static_assert(T_LEN % 2 == 0, "pipeline parity assumes even T");

typedef _Float16 f16x2v __attribute__((ext_vector_type(2)));

#if __has_builtin(__builtin_amdgcn_fdot2)
static __device__ __forceinline__ float dot2f(__half2 w, __half2 h, float acc) {
    return __builtin_amdgcn_fdot2(__builtin_bit_cast(f16x2v, w),
                                  __builtin_bit_cast(f16x2v, h), acc, false);
}
#else
static __device__ __forceinline__ float dot2f(__half2 w, __half2 h, float acc) {
    float2 wf = __half22float2(w), hf = __half22float2(h);
    return fmaf(wf.y, hf.y, fmaf(wf.x, hf.x, acc));
}
#endif

// ======================= gx = x @ W_ih^T + biases (folded) =======================
// r/z rows get b_ih+b_hh folded; n rows get b_ih only (b_hh_n added h-side in scan).
__global__ __launch_bounds__(256) void gx_kernel(const float* __restrict__ x,
                                                 const float* __restrict__ W_ih,
                                                 const float* __restrict__ b_ih,
                                                 const float* __restrict__ b_hh,
                                                 float* __restrict__ gx)
{
    __shared__ float xs[64][68];
    __shared__ float ws[64][68];
    const int t0 = blockIdx.x * 64;
    const int g0 = blockIdx.y * 64;
    const int tid = threadIdx.x;

#pragma unroll
    for (int i = 0; i < 16; ++i) {
        int idx = tid + i * 256;
        int m = idx >> 6, k = idx & 63;
        xs[k][m] = x[(size_t)(t0 + m) * 64 + k];
        ws[k][m] = W_ih[(size_t)(g0 + m) * 64 + k];
    }
    __syncthreads();

    const int tx = tid & 15, ty = tid >> 4;
    float acc[4][4] = {};
#pragma unroll 8
    for (int k = 0; k < 64; ++k) {
        float4 av = *reinterpret_cast<const float4*>(&xs[k][ty * 4]);
        float4 bv = *reinterpret_cast<const float4*>(&ws[k][tx * 4]);
        float a4[4] = {av.x, av.y, av.z, av.w};
        float b4[4] = {bv.x, bv.y, bv.z, bv.w};
#pragma unroll
        for (int i = 0; i < 4; ++i)
#pragma unroll
            for (int j = 0; j < 4; ++j)
                acc[i][j] = fmaf(a4[i], b4[j], acc[i][j]);
    }

#pragma unroll
    for (int i = 0; i < 4; ++i) {
        float4 o;
        float* op = &o.x;
#pragma unroll
        for (int j = 0; j < 4; ++j) {
            int g = g0 + tx * 4 + j;
            float bias = b_ih[g] + ((g < 2 * HID) ? b_hh[g] : 0.0f);
            op[j] = acc[i][j] + bias;
        }
        *reinterpret_cast<float4*>(&gx[(size_t)(t0 + ty * 4 + i) * G3 + g0 + tx * 4]) = o;
    }
}

// ======================= scan kernel (1 block, 768 threads) =======================
// gx precomputed in ws; loop = W_hh matvec + gates. Weights MUST be register-resident:
// amdgpu_waves_per_eu(3) pins the VGPR cap at 512/3=168 (launch_bounds(768,3) was
// mis-handled as min-BLOCKS by hipcc -> 84-reg cap -> 505KB/step scratch spill traffic).
__global__
__attribute__((amdgpu_flat_work_group_size(768, 768)))
__attribute__((amdgpu_waves_per_eu(3)))
void scan_kernel(const float* __restrict__ gx,
                 const float* __restrict__ W_hh,
                 const float* __restrict__ b_hh,
                 __half* __restrict__ hs)
{
    __shared__ __align__(16) __half hl2[2][HID];   // double-buffered h (f16)
    __shared__ float ghl[G3];                      // reduced h-side preacts

    const int tid = threadIdx.x;
    const int sp  = tid & 7;       // col split 0..7 (32 cols each)
    const int rg  = tid >> 3;      // row group 0..95 (8 rows each)
    const int b0 = sp & 1, b1 = (sp >> 1) & 1, b2 = (sp >> 2) & 1;
    const int rot = sp >> 1;       // chunk rotation: conflict-free h reads

    // ---- W_hh: 8 rows x 32 cols per thread, f16 pairs, rotated chunk slots ----
    // 128 VGPRs; register-resident is the entire point of this kernel.
    __half2 w[8][16];
#pragma unroll
    for (int c = 0; c < 4; ++c) {
        const int cp = (c + rot) & 3;
#pragma unroll
        for (int q = 0; q < 4; ++q)
#pragma unroll
            for (int r = 0; r < 8; ++r) {
                const float* wr = W_hh + (size_t)(rg * 8 + r) * HID + sp * 32 + cp * 8 + 2 * q;
                w[r][c * 4 + q] = __floats2half2_rn(wr[0], wr[1]);
            }
    }

    // h-side bias for n rows only (r/z h-biases were folded into gx).
    const bool nrow = (tid >= 2 * HID);   // wave-uniform (waves 8..11)
    const float bh_own = nrow ? b_hh[tid] : 0.f;

    // ---- prologue: h_{-1}=0 in buffer 1; prefetch gx[0] ----
    if (tid < HID) hl2[1][tid] = __float2half(0.f);
    float pfr = 0.f, pfz = 0.f, pfn = 0.f;
    if (tid < HID) {
        pfr = gx[tid];
        pfz = gx[HID + tid];
        pfn = gx[2 * HID + tid];
    }
    __syncthreads();

    float h = 0.f;
    const float* gxp = gx + G3 + tid;      // next-step prefetch base (t=1)
    __half* hsp = hs + tid;                // own hs column

    for (int t = 0; t < T_LEN; ++t) {
        const int cur = t & 1, pb = cur ^ 1;

        // ---- phase A: partial gh = W_hh @ h over this thread's 32 cols ----
        float acc[8];
#pragma unroll
        for (int r = 0; r < 8; ++r) acc[r] = 0.f;

        {
            const float4* hp = reinterpret_cast<const float4*>(hl2[pb]);
#pragma unroll
            for (int c = 0; c < 4; ++c) {
                const int cp = (c + rot) & 3;
                union { float4 f4; __half2 h2[4]; } hv;
                hv.f4 = hp[sp * 4 + cp];
#pragma unroll
                for (int q = 0; q < 4; ++q)
#pragma unroll
                    for (int r = 0; r < 8; ++r)
                        acc[r] = dot2f(w[r][c * 4 + q], hv.h2[q], acc[r]);
            }
        }

        // ---- reduce-scatter butterfly over 8 split lanes -> row tid (in place) ----
        {
#pragma unroll
            for (int i = 0; i < 4; ++i) {
                float snd = b0 ? acc[2 * i] : acc[2 * i + 1];
                float rcv = __shfl_xor(snd, 1, 64);
                float kep = b0 ? acc[2 * i + 1] : acc[2 * i];
                acc[i] = kep + rcv;
            }
#pragma unroll
            for (int i = 0; i < 2; ++i) {
                float snd = b1 ? acc[2 * i] : acc[2 * i + 1];
                float rcv = __shfl_xor(snd, 2, 64);
                float kep = b1 ? acc[2 * i + 1] : acc[2 * i];
                acc[i] = kep + rcv;
            }
            float snd = b2 ? acc[0] : acc[1];
            float rcv = __shfl_xor(snd, 4, 64);
            float kep = b2 ? acc[1] : acc[0];
            ghl[tid] = kep + rcv + bh_own;
        }
        __syncthreads();

        // ---- phase B: gates + state update (threads 0..255 = waves 0..3) ----
        if (tid < HID) {
            float gr  = pfr + ghl[tid];
            float gz  = pfz + ghl[HID + tid];
            float ghn = ghl[2 * HID + tid];
            float gxn = pfn;

            // prefetch next step's gx (full step of latency cover)
            pfr = gxp[0];
            pfz = gxp[HID];
            pfn = gxp[2 * HID];
            if (t + 2 < T_LEN) gxp += G3;

            float rr = 1.f / (1.f + __expf(-gr));
            float zz = 1.f / (1.f + __expf(-gz));
            float pre = fmaf(rr, ghn, gxn);
            float ap = fabsf(pre);
            float e2 = __expf(-2.f * ap);
            float nn = __builtin_copysignf((1.f - e2) / (1.f + e2), pre);
            h = fmaf(zz, h - nn, nn);       // (1-z)*n + z*h

            __half hq = __float2half(h);
            hl2[cur][tid] = hq;
            *hsp = hq;
            hsp += HID;
        }
        __syncthreads();
    }
}

// ======================= out = hs(f16) @ W_fc^T + b_fc =======================
__global__ __launch_bounds__(256) void fc_kernel(const __half* __restrict__ hs,
                                                 const float* __restrict__ W_fc,
                                                 const float* __restrict__ b_fc,
                                                 float* __restrict__ out)
{
    __shared__ float as[64][68];
    __shared__ float bs[64][68];
    const int t0 = blockIdx.x * 64;
    const int tid = threadIdx.x;
    const int tx = tid & 15, ty = tid >> 4;
    float acc[4][4] = {};

    for (int kk = 0; kk < HID; kk += 64) {
        __syncthreads();
#pragma unroll
        for (int i = 0; i < 16; ++i) {
            int idx = tid + i * 256;
            int m = idx >> 6, k = idx & 63;
            as[k][m] = __half2float(hs[(size_t)(t0 + m) * HID + kk + k]);
            bs[k][m] = W_fc[(size_t)m * HID + kk + k];
        }
        __syncthreads();
#pragma unroll 8
        for (int k = 0; k < 64; ++k) {
            float4 av = *reinterpret_cast<const float4*>(&as[k][ty * 4]);
            float4 bv = *reinterpret_cast<const float4*>(&bs[k][tx * 4]);
            float a4[4] = {av.x, av.y, av.z, av.w};
            float b4[4] = {bv.x, bv.y, bv.z, bv.w};
#pragma unroll
            for (int i = 0; i < 4; ++i)
#pragma unroll
                for (int j = 0; j < 4; ++j)
                    acc[i][j] = fmaf(a4[i], b4[j], acc[i][j]);
        }
    }

#pragma unroll
    for (int i = 0; i < 4; ++i) {
        float4 o;
        float* op = &o.x;
#pragma unroll
        for (int j = 0; j < 4; ++j)
            op[j] = acc[i][j] + b_fc[tx * 4 + j];
        *reinterpret_cast<float4*>(&out[(size_t)(t0 + ty * 4 + i) * 64 + tx * 4]) = o;
    }
}

// ======================= fallback monolith (proven PASS @846ms) =======================
__global__ __launch_bounds__(768) void gru_fused(const float* __restrict__ x,
                                                 const float* __restrict__ W_ih,
                                                 const float* __restrict__ W_hh,
                                                 const float* __restrict__ b_ih,
                                                 const float* __restrict__ b_hh,
                                                 const float* __restrict__ W_fc,
                                                 const float* __restrict__ b_fc,
                                                 float* __restrict__ out)
{
    __shared__ __align__(16) __half hl2[2][HID];
    __shared__ __align__(16) __half xb[2][64];
    __shared__ float ghl[G3];
    __shared__ float gxnl[HID];

    const int tid = threadIdx.x;
    const int sp  = tid & 7;
    const int rg  = tid >> 3;
    const int b0 = sp & 1, b1 = (sp >> 1) & 1, b2 = (sp >> 2) & 1;
    const int rot = sp >> 1;

    __half2 w[8][16];
#pragma unroll
    for (int c = 0; c < 4; ++c) {
        const int cp = (c + rot) & 3;
#pragma unroll
        for (int q = 0; q < 4; ++q)
#pragma unroll
            for (int r = 0; r < 8; ++r) {
                const float* wr = W_hh + (size_t)(rg * 8 + r) * HID + sp * 32 + cp * 8 + 2 * q;
                w[r][c * 4 + q] = __floats2half2_rn(wr[0], wr[1]);
            }
    }
    __half2 wih[8][4];
#pragma unroll
    for (int r = 0; r < 8; ++r)
#pragma unroll
        for (int q = 0; q < 4; ++q) {
            const float* p = W_ih + (size_t)(rg * 8 + r) * 64 + sp * 8 + 2 * q;
            wih[r][q] = __floats2half2_rn(p[0], p[1]);
        }
    const int u = tid - 256;
    __half2 wfc[32];
    float bfc = 0.f;
    int fo = 0, fq = 0;
    if (u >= 0 && u < 256) {
        fo = u >> 2; fq = u & 3;
#pragma unroll
        for (int j = 0; j < 32; ++j) {
            const float* p = W_fc + (size_t)fo * HID + fq * 64 + 2 * j;
            wfc[j] = __floats2half2_rn(p[0], p[1]);
        }
        bfc = b_fc[fo];
    }
    const bool nrow = (tid >= 2 * HID);
    float bh_merged = 0.f, bh_n = 0.f, bi_n = 0.f;
    if (!nrow) bh_merged = b_ih[tid] + b_hh[tid];
    else { bh_n = b_hh[tid]; bi_n = b_ih[tid]; }

    if (tid < HID) hl2[1][tid] = __float2half(0.f);
    float4 xreg = make_float4(0.f, 0.f, 0.f, 0.f);
    if (tid < 16) {
        float4 x0 = *reinterpret_cast<const float4*>(x + tid * 4);
        __half2* dst = reinterpret_cast<__half2*>(&xb[0][tid * 4]);
        dst[0] = __floats2half2_rn(x0.x, x0.y);
        dst[1] = __floats2half2_rn(x0.z, x0.w);
        xreg = *reinterpret_cast<const float4*>(x + 64 + tid * 4);
    }
    __syncthreads();

    float h = 0.f;
    for (int t = 0; t < T_LEN; ++t) {
        const int cur = t & 1, pb = cur ^ 1;
        float acc[8], accx[8];
#pragma unroll
        for (int r = 0; r < 8; ++r) { acc[r] = 0.f; accx[r] = 0.f; }
        {
            union { float4 f4; __half2 h2[4]; } xv;
            xv.f4 = reinterpret_cast<const float4*>(xb[cur])[sp];
#pragma unroll
            for (int q = 0; q < 4; ++q)
#pragma unroll
                for (int r = 0; r < 8; ++r)
                    accx[r] = dot2f(wih[r][q], xv.h2[q], accx[r]);
        }
        {
            const float4* hp = reinterpret_cast<const float4*>(hl2[pb]);
#pragma unroll
            for (int c = 0; c < 4; ++c) {
                const int cp = (c + rot) & 3;
                union { float4 f4; __half2 h2[4]; } hv;
                hv.f4 = hp[sp * 4 + cp];
#pragma unroll
                for (int q = 0; q < 4; ++q)
#pragma unroll
                    for (int r = 0; r < 8; ++r)
                        acc[r] = dot2f(w[r][c * 4 + q], hv.h2[q], acc[r]);
            }
        }
        if (!nrow) {
#pragma unroll
            for (int r = 0; r < 8; ++r) acc[r] += accx[r];
        }
        {
            float v4[4];
#pragma unroll
            for (int i = 0; i < 4; ++i) {
                float snd = b0 ? acc[2 * i] : acc[2 * i + 1];
                float rcv = __shfl_xor(snd, 1, 64);
                float kep = b0 ? acc[2 * i + 1] : acc[2 * i];
                v4[i] = kep + rcv;
            }
            float v2[2];
#pragma unroll
            for (int i = 0; i < 2; ++i) {
                float snd = b1 ? v4[2 * i] : v4[2 * i + 1];
                float rcv = __shfl_xor(snd, 2, 64);
                float kep = b1 ? v4[2 * i + 1] : v4[2 * i];
                v2[i] = kep + rcv;
            }
            float snd = b2 ? v2[0] : v2[1];
            float rcv = __shfl_xor(snd, 4, 64);
            float kep = b2 ? v2[1] : v2[0];
            ghl[tid] = kep + rcv + (nrow ? bh_n : bh_merged);
        }
        if (nrow) {
            float v4[4];
#pragma unroll
            for (int i = 0; i < 4; ++i) {
                float snd = b0 ? accx[2 * i] : accx[2 * i + 1];
                float rcv = __shfl_xor(snd, 1, 64);
                float kep = b0 ? accx[2 * i + 1] : accx[2 * i];
                v4[i] = kep + rcv;
            }
            float v2[2];
#pragma unroll
            for (int i = 0; i < 2; ++i) {
                float snd = b1 ? v4[2 * i] : v4[2 * i + 1];
                float rcv = __shfl_xor(snd, 2, 64);
                float kep = b1 ? v4[2 * i + 1] : v4[2 * i];
                v2[i] = kep + rcv;
            }
            float snd = b2 ? v2[0] : v2[1];
            float rcv = __shfl_xor(snd, 4, 64);
            float kep = b2 ? v2[1] : v2[0];
            gxnl[tid - 2 * HID] = kep + rcv + bi_n;
        }
        __syncthreads();

        if (tid < HID) {
            float gr  = ghl[tid];
            float gz  = ghl[HID + tid];
            float ghn = ghl[2 * HID + tid];
            float gxn = gxnl[tid];
            float rr = 1.f / (1.f + __expf(-gr));
            float zz = 1.f / (1.f + __expf(-gz));
            float pre = fmaf(rr, ghn, gxn);
            float ap = fabsf(pre);
            float e2 = __expf(-2.f * ap);
            float nn = __builtin_copysignf((1.f - e2) / (1.f + e2), pre);
            h = fmaf(zz, h - nn, nn);
            hl2[cur][tid] = __float2half(h);
            if (tid < 16) {
                __half2* dst = reinterpret_cast<__half2*>(&xb[pb][tid * 4]);
                dst[0] = __floats2half2_rn(xreg.x, xreg.y);
                dst[1] = __floats2half2_rn(xreg.z, xreg.w);
                int tn = (t + 2 < T_LEN) ? t + 2 : T_LEN - 1;
                xreg = *reinterpret_cast<const float4*>(x + (size_t)tn * 64 + tid * 4);
            }
        } else if (u < 256) {
            if (t > 0) {
                const float4* hv4 = reinterpret_cast<const float4*>(hl2[pb]);
                float fa = 0.f;
#pragma unroll
                for (int j = 0; j < 8; ++j) {
                    union { float4 f4; __half2 h2[4]; } hh;
                    hh.f4 = hv4[fq * 8 + j];
#pragma unroll
                    for (int k2 = 0; k2 < 4; ++k2)
                        fa = dot2f(wfc[j * 4 + k2], hh.h2[k2], fa);
                }
                fa += __shfl_xor(fa, 1, 64);
                fa += __shfl_xor(fa, 2, 64);
                if (fq == 0) out[(size_t)(t - 1) * 64 + fo] = fa + bfc;
            }
        }
        __syncthreads();
    }

    if (u >= 0 && u < 256) {
        const float4* hv4 = reinterpret_cast<const float4*>(hl2[1]);
        float fa = 0.f;
#pragma unroll
        for (int j = 0; j < 8; ++j) {
            union { float4 f4; __half2 h2[4]; } hh;
            hh.f4 = hv4[fq * 8 + j];
#pragma unroll
            for (int k2 = 0; k2 < 4; ++k2)
                fa = dot2f(wfc[j * 4 + k2], hh.h2[k2], fa);
        }
        fa += __shfl_xor(fa, 1, 64);
        fa += __shfl_xor(fa, 2, 64);
        if (fq == 0) out[(size_t)(T_LEN - 1) * 64 + fo] = fa + bfc;
    }
}

extern "C" void kernel_launch(void* const* d_in, const int* in_sizes, int n_in,
                              void* d_out, int out_size, void* d_ws, size_t ws_size,
                              hipStream_t stream)
{
    const float* x    = (const float*)d_in[0];
    const float* W_ih = (const float*)d_in[1];
    const float* W_hh = (const float*)d_in[2];
    const float* b_ih = (const float*)d_in[3];
    const float* b_hh = (const float*)d_in[4];
    const float* W_fc = (const float*)d_in[5];
    const float* b_fc = (const float*)d_in[6];
    float* out = (float*)d_out;

    const size_t GX_BYTES = (size_t)T_LEN * G3 * sizeof(float);    // 384 MiB
    const size_t HS_BYTES = (size_t)T_LEN * HID * sizeof(__half);  // 64 MiB

    if (ws_size >= GX_BYTES + HS_BYTES) {
        // Path A: gx precomputed, lean register-resident scan, separate FC
        float*  gx = (float*)d_ws;
        __half* hs = (__half*)((char*)d_ws + GX_BYTES);
        gx_kernel<<<dim3(T_LEN / 64, G3 / 64), dim3(256), 0, stream>>>(x, W_ih, b_ih, b_hh, gx);
        scan_kernel<<<dim3(1), dim3(768), 0, stream>>>(gx, W_hh, b_hh, hs);
        fc_kernel<<<dim3(T_LEN / 64), dim3(256), 0, stream>>>(hs, W_fc, b_fc, out);
    } else {
        // Path C: proven fully-fused fallback
        gru_fused<<<dim3(1), dim3(768), 0, stream>>>(x, W_ih, W_hh, b_ih, b_hh, W_fc, b_fc, out);
    }
}

// Round 6
// 172066.968 us; speedup vs baseline: 4.9687x; 4.9687x over previous
//
#include <hip/hip_runtime.h>
#include <hip/hip_fp16.h>

#define T_LEN 131072
#define HID 256
#define G3 768     // 3*HID
#define TC 8192    // chunk length (T_LEN/TC chunks)

static_assert(T_LEN % TC == 0, "chunking");
static_assert(TC % 64 == 0, "gx/fc tiling");
static_assert(TC % 2 == 0, "h double-buffer parity");

typedef _Float16 f16x2v __attribute__((ext_vector_type(2)));

#if __has_builtin(__builtin_amdgcn_fdot2)
static __device__ __forceinline__ float dot2f(__half2 w, __half2 h, float acc) {
    return __builtin_amdgcn_fdot2(__builtin_bit_cast(f16x2v, w),
                                  __builtin_bit_cast(f16x2v, h), acc, false);
}
#else
static __device__ __forceinline__ float dot2f(__half2 w, __half2 h, float acc) {
    float2 wf = __half22float2(w), hf = __half22float2(h);
    return fmaf(wf.y, hf.y, fmaf(wf.x, hf.x, acc));
}
#endif

// ============ gx_chunk = x_chunk @ W_ih^T + biases (r/z: b_ih+b_hh; n: b_ih) ============
__global__ __launch_bounds__(256) void gx_kernel(const float* __restrict__ x,   // chunk base
                                                 const float* __restrict__ W_ih,
                                                 const float* __restrict__ b_ih,
                                                 const float* __restrict__ b_hh,
                                                 float* __restrict__ gx)        // [TC][G3]
{
    __shared__ float xs[64][68];
    __shared__ float ws[64][68];
    const int t0 = blockIdx.x * 64;        // local t within chunk
    const int g0 = blockIdx.y * 64;
    const int tid = threadIdx.x;

#pragma unroll
    for (int i = 0; i < 16; ++i) {
        int idx = tid + i * 256;
        int m = idx >> 6, k = idx & 63;
        xs[k][m] = x[(size_t)(t0 + m) * 64 + k];
        ws[k][m] = W_ih[(size_t)(g0 + m) * 64 + k];
    }
    __syncthreads();

    const int tx = tid & 15, ty = tid >> 4;
    float acc[4][4] = {};
#pragma unroll 8
    for (int k = 0; k < 64; ++k) {
        float4 av = *reinterpret_cast<const float4*>(&xs[k][ty * 4]);
        float4 bv = *reinterpret_cast<const float4*>(&ws[k][tx * 4]);
        float a4[4] = {av.x, av.y, av.z, av.w};
        float b4[4] = {bv.x, bv.y, bv.z, bv.w};
#pragma unroll
        for (int i = 0; i < 4; ++i)
#pragma unroll
            for (int j = 0; j < 4; ++j)
                acc[i][j] = fmaf(a4[i], b4[j], acc[i][j]);
    }

#pragma unroll
    for (int i = 0; i < 4; ++i) {
        float4 o;
        float* op = &o.x;
#pragma unroll
        for (int j = 0; j < 4; ++j) {
            int g = g0 + tx * 4 + j;
            float bias = b_ih[g] + ((g < 2 * HID) ? b_hh[g] : 0.0f);
            op[j] = acc[i][j] + bias;
        }
        *reinterpret_cast<float4*>(&gx[(size_t)(t0 + ty * 4 + i) * G3 + g0 + tx * 4]) = o;
    }
}

// ============ scan over one chunk: 1 block, 768 threads, W_hh register-resident ============
// amdgpu_waves_per_eu(3,3): 12 waves need 3 waves/SIMD co-resident -> VGPR cap 512/3=170.
// (__launch_bounds__(768,3) gave an 84-reg cap in r4 -> 505 KB/step scratch spill traffic.)
__global__
__attribute__((amdgpu_flat_work_group_size(768, 768)))
__attribute__((amdgpu_waves_per_eu(3, 3)))
void scan_chunk(const float* __restrict__ gx,     // [TC][G3] this chunk
                const float* __restrict__ W_hh,
                const float* __restrict__ b_hh,
                __half* __restrict__ hs,          // [TC][HID] this chunk
                float* __restrict__ h_state,      // [HID] carried across chunks
                int first)
{
    __shared__ __align__(16) __half hl2[2][HID];   // double-buffered h (f16)
    __shared__ float ghl[G3];                      // reduced h-side preacts

    const int tid = threadIdx.x;
    const int sp  = tid & 7;       // col split 0..7 (32 cols each)
    const int rg  = tid >> 3;      // row group 0..95 (8 rows each)
    const int b0 = sp & 1, b1 = (sp >> 1) & 1, b2 = (sp >> 2) & 1;
    const int rot = sp >> 1;       // chunk rotation: conflict-free h reads

    // ---- W_hh: 8 rows x 32 cols per thread, f16 pairs, rotated chunk slots (128 VGPRs) ----
    __half2 w[8][16];
#pragma unroll
    for (int c = 0; c < 4; ++c) {
        const int cp = (c + rot) & 3;
#pragma unroll
        for (int q = 0; q < 4; ++q)
#pragma unroll
            for (int r = 0; r < 8; ++r) {
                const float* wr = W_hh + (size_t)(rg * 8 + r) * HID + sp * 32 + cp * 8 + 2 * q;
                w[r][c * 4 + q] = __floats2half2_rn(wr[0], wr[1]);
            }
    }

    // h-side bias for n rows only (r/z h-biases folded into gx).
    const bool nrow = (tid >= 2 * HID);   // wave-uniform (waves 8..11)
    const float bh_own = nrow ? b_hh[tid] : 0.f;

    // ---- prologue: restore h; prefetch gx row 0 ----
    float h = 0.f;
    float pfr = 0.f, pfz = 0.f, pfn = 0.f;
    if (tid < HID) {
        h = first ? 0.f : h_state[tid];
        hl2[1][tid] = __float2half(h);
        pfr = gx[tid];
        pfz = gx[HID + tid];
        pfn = gx[2 * HID + tid];
    }
    __syncthreads();

    const float* gxp = gx + G3 + tid;      // next-step prefetch base (row 1)
    __half* hsp = hs + tid;                // own hs column

    for (int t = 0; t < TC; ++t) {
        const int cur = t & 1, pb = cur ^ 1;

        // ---- phase A: partial gh = W_hh @ h over this thread's 32 cols ----
        float acc[8];
#pragma unroll
        for (int r = 0; r < 8; ++r) acc[r] = 0.f;

        {
            const float4* hp = reinterpret_cast<const float4*>(hl2[pb]);
#pragma unroll
            for (int c = 0; c < 4; ++c) {
                const int cp = (c + rot) & 3;
                union { float4 f4; __half2 h2[4]; } hv;
                hv.f4 = hp[sp * 4 + cp];
#pragma unroll
                for (int q = 0; q < 4; ++q)
#pragma unroll
                    for (int r = 0; r < 8; ++r)
                        acc[r] = dot2f(w[r][c * 4 + q], hv.h2[q], acc[r]);
            }
        }

        // ---- reduce-scatter butterfly over 8 split lanes -> row tid (in place) ----
        {
#pragma unroll
            for (int i = 0; i < 4; ++i) {
                float snd = b0 ? acc[2 * i] : acc[2 * i + 1];
                float rcv = __shfl_xor(snd, 1, 64);
                float kep = b0 ? acc[2 * i + 1] : acc[2 * i];
                acc[i] = kep + rcv;
            }
#pragma unroll
            for (int i = 0; i < 2; ++i) {
                float snd = b1 ? acc[2 * i] : acc[2 * i + 1];
                float rcv = __shfl_xor(snd, 2, 64);
                float kep = b1 ? acc[2 * i + 1] : acc[2 * i];
                acc[i] = kep + rcv;
            }
            float snd = b2 ? acc[0] : acc[1];
            float rcv = __shfl_xor(snd, 4, 64);
            float kep = b2 ? acc[1] : acc[0];
            ghl[tid] = kep + rcv + bh_own;
        }
        __syncthreads();

        // ---- phase B: gates + state update (threads 0..255 = waves 0..3) ----
        if (tid < HID) {
            float gr  = pfr + ghl[tid];
            float gz  = pfz + ghl[HID + tid];
            float ghn = ghl[2 * HID + tid];
            float gxn = pfn;

            // prefetch next step's gx (full matvec phase of latency cover)
            pfr = gxp[0];
            pfz = gxp[HID];
            pfn = gxp[2 * HID];
            if (t + 2 < TC) gxp += G3;

            float rr = 1.f / (1.f + __expf(-gr));
            float zz = 1.f / (1.f + __expf(-gz));
            float pre = fmaf(rr, ghn, gxn);
            float ap = fabsf(pre);
            float e2 = __expf(-2.f * ap);
            float nn = __builtin_copysignf((1.f - e2) / (1.f + e2), pre);
            h = fmaf(zz, h - nn, nn);       // (1-z)*n + z*h

            __half hq = __float2half(h);
            hl2[cur][tid] = hq;
            *hsp = hq;
            hsp += HID;
        }
        __syncthreads();
    }

    if (tid < HID) h_state[tid] = h;       // carry f32 state to next chunk
}

// ============ out_chunk = hs_chunk(f16) @ W_fc^T + b_fc ============
__global__ __launch_bounds__(256) void fc_kernel(const __half* __restrict__ hs,  // [TC][HID]
                                                 const float* __restrict__ W_fc,
                                                 const float* __restrict__ b_fc,
                                                 float* __restrict__ out)        // chunk base
{
    __shared__ float as[64][68];
    __shared__ float bs[64][68];
    const int t0 = blockIdx.x * 64;
    const int tid = threadIdx.x;
    const int tx = tid & 15, ty = tid >> 4;
    float acc[4][4] = {};

    for (int kk = 0; kk < HID; kk += 64) {
        __syncthreads();
#pragma unroll
        for (int i = 0; i < 16; ++i) {
            int idx = tid + i * 256;
            int m = idx >> 6, k = idx & 63;
            as[k][m] = __half2float(hs[(size_t)(t0 + m) * HID + kk + k]);
            bs[k][m] = W_fc[(size_t)m * HID + kk + k];
        }
        __syncthreads();
#pragma unroll 8
        for (int k = 0; k < 64; ++k) {
            float4 av = *reinterpret_cast<const float4*>(&as[k][ty * 4]);
            float4 bv = *reinterpret_cast<const float4*>(&bs[k][tx * 4]);
            float a4[4] = {av.x, av.y, av.z, av.w};
            float b4[4] = {bv.x, bv.y, bv.z, bv.w};
#pragma unroll
            for (int i = 0; i < 4; ++i)
#pragma unroll
                for (int j = 0; j < 4; ++j)
                    acc[i][j] = fmaf(a4[i], b4[j], acc[i][j]);
        }
    }

#pragma unroll
    for (int i = 0; i < 4; ++i) {
        float4 o;
        float* op = &o.x;
#pragma unroll
        for (int j = 0; j < 4; ++j)
            op[j] = acc[i][j] + b_fc[tx * 4 + j];
        *reinterpret_cast<float4*>(&out[(size_t)(t0 + ty * 4 + i) * 64 + tx * 4]) = o;
    }
}

// ============ fallback monolith (proven PASS @846ms) ============
__global__ __launch_bounds__(768) void gru_fused(const float* __restrict__ x,
                                                 const float* __restrict__ W_ih,
                                                 const float* __restrict__ W_hh,
                                                 const float* __restrict__ b_ih,
                                                 const float* __restrict__ b_hh,
                                                 const float* __restrict__ W_fc,
                                                 const float* __restrict__ b_fc,
                                                 float* __restrict__ out)
{
    __shared__ __align__(16) __half hl2[2][HID];
    __shared__ __align__(16) __half xb[2][64];
    __shared__ float ghl[G3];
    __shared__ float gxnl[HID];

    const int tid = threadIdx.x;
    const int sp  = tid & 7;
    const int rg  = tid >> 3;
    const int b0 = sp & 1, b1 = (sp >> 1) & 1, b2 = (sp >> 2) & 1;
    const int rot = sp >> 1;

    __half2 w[8][16];
#pragma unroll
    for (int c = 0; c < 4; ++c) {
        const int cp = (c + rot) & 3;
#pragma unroll
        for (int q = 0; q < 4; ++q)
#pragma unroll
            for (int r = 0; r < 8; ++r) {
                const float* wr = W_hh + (size_t)(rg * 8 + r) * HID + sp * 32 + cp * 8 + 2 * q;
                w[r][c * 4 + q] = __floats2half2_rn(wr[0], wr[1]);
            }
    }
    __half2 wih[8][4];
#pragma unroll
    for (int r = 0; r < 8; ++r)
#pragma unroll
        for (int q = 0; q < 4; ++q) {
            const float* p = W_ih + (size_t)(rg * 8 + r) * 64 + sp * 8 + 2 * q;
            wih[r][q] = __floats2half2_rn(p[0], p[1]);
        }
    const int u = tid - 256;
    __half2 wfc[32];
    float bfc = 0.f;
    int fo = 0, fq = 0;
    if (u >= 0 && u < 256) {
        fo = u >> 2; fq = u & 3;
#pragma unroll
        for (int j = 0; j < 32; ++j) {
            const float* p = W_fc + (size_t)fo * HID + fq * 64 + 2 * j;
            wfc[j] = __floats2half2_rn(p[0], p[1]);
        }
        bfc = b_fc[fo];
    }
    const bool nrow = (tid >= 2 * HID);
    float bh_merged = 0.f, bh_n = 0.f, bi_n = 0.f;
    if (!nrow) bh_merged = b_ih[tid] + b_hh[tid];
    else { bh_n = b_hh[tid]; bi_n = b_ih[tid]; }

    if (tid < HID) hl2[1][tid] = __float2half(0.f);
    float4 xreg = make_float4(0.f, 0.f, 0.f, 0.f);
    if (tid < 16) {
        float4 x0 = *reinterpret_cast<const float4*>(x + tid * 4);
        __half2* dst = reinterpret_cast<__half2*>(&xb[0][tid * 4]);
        dst[0] = __floats2half2_rn(x0.x, x0.y);
        dst[1] = __floats2half2_rn(x0.z, x0.w);
        xreg = *reinterpret_cast<const float4*>(x + 64 + tid * 4);
    }
    __syncthreads();

    float h = 0.f;
    for (int t = 0; t < T_LEN; ++t) {
        const int cur = t & 1, pb = cur ^ 1;
        float acc[8], accx[8];
#pragma unroll
        for (int r = 0; r < 8; ++r) { acc[r] = 0.f; accx[r] = 0.f; }
        {
            union { float4 f4; __half2 h2[4]; } xv;
            xv.f4 = reinterpret_cast<const float4*>(xb[cur])[sp];
#pragma unroll
            for (int q = 0; q < 4; ++q)
#pragma unroll
                for (int r = 0; r < 8; ++r)
                    accx[r] = dot2f(wih[r][q], xv.h2[q], accx[r]);
        }
        {
            const float4* hp = reinterpret_cast<const float4*>(hl2[pb]);
#pragma unroll
            for (int c = 0; c < 4; ++c) {
                const int cp = (c + rot) & 3;
                union { float4 f4; __half2 h2[4]; } hv;
                hv.f4 = hp[sp * 4 + cp];
#pragma unroll
                for (int q = 0; q < 4; ++q)
#pragma unroll
                    for (int r = 0; r < 8; ++r)
                        acc[r] = dot2f(w[r][c * 4 + q], hv.h2[q], acc[r]);
            }
        }
        if (!nrow) {
#pragma unroll
            for (int r = 0; r < 8; ++r) acc[r] += accx[r];
        }
        {
            float v4[4];
#pragma unroll
            for (int i = 0; i < 4; ++i) {
                float snd = b0 ? acc[2 * i] : acc[2 * i + 1];
                float rcv = __shfl_xor(snd, 1, 64);
                float kep = b0 ? acc[2 * i + 1] : acc[2 * i];
                v4[i] = kep + rcv;
            }
            float v2[2];
#pragma unroll
            for (int i = 0; i < 2; ++i) {
                float snd = b1 ? v4[2 * i] : v4[2 * i + 1];
                float rcv = __shfl_xor(snd, 2, 64);
                float kep = b1 ? v4[2 * i + 1] : v4[2 * i];
                v2[i] = kep + rcv;
            }
            float snd = b2 ? v2[0] : v2[1];
            float rcv = __shfl_xor(snd, 4, 64);
            float kep = b2 ? v2[1] : v2[0];
            ghl[tid] = kep + rcv + (nrow ? bh_n : bh_merged);
        }
        if (nrow) {
            float v4[4];
#pragma unroll
            for (int i = 0; i < 4; ++i) {
                float snd = b0 ? accx[2 * i] : accx[2 * i + 1];
                float rcv = __shfl_xor(snd, 1, 64);
                float kep = b0 ? accx[2 * i + 1] : accx[2 * i];
                v4[i] = kep + rcv;
            }
            float v2[2];
#pragma unroll
            for (int i = 0; i < 2; ++i) {
                float snd = b1 ? v4[2 * i] : v4[2 * i + 1];
                float rcv = __shfl_xor(snd, 2, 64);
                float kep = b1 ? v4[2 * i + 1] : v4[2 * i];
                v2[i] = kep + rcv;
            }
            float snd = b2 ? v2[0] : v2[1];
            float rcv = __shfl_xor(snd, 4, 64);
            float kep = b2 ? v2[1] : v2[0];
            gxnl[tid - 2 * HID] = kep + rcv + bi_n;
        }
        __syncthreads();

        if (tid < HID) {
            float gr  = ghl[tid];
            float gz  = ghl[HID + tid];
            float ghn = ghl[2 * HID + tid];
            float gxn = gxnl[tid];
            float rr = 1.f / (1.f + __expf(-gr));
            float zz = 1.f / (1.f + __expf(-gz));
            float pre = fmaf(rr, ghn, gxn);
            float ap = fabsf(pre);
            float e2 = __expf(-2.f * ap);
            float nn = __builtin_copysignf((1.f - e2) / (1.f + e2), pre);
            h = fmaf(zz, h - nn, nn);
            hl2[cur][tid] = __float2half(h);
            if (tid < 16) {
                __half2* dst = reinterpret_cast<__half2*>(&xb[pb][tid * 4]);
                dst[0] = __floats2half2_rn(xreg.x, xreg.y);
                dst[1] = __floats2half2_rn(xreg.z, xreg.w);
                int tn = (t + 2 < T_LEN) ? t + 2 : T_LEN - 1;
                xreg = *reinterpret_cast<const float4*>(x + (size_t)tn * 64 + tid * 4);
            }
        } else if (u < 256) {
            if (t > 0) {
                const float4* hv4 = reinterpret_cast<const float4*>(hl2[pb]);
                float fa = 0.f;
#pragma unroll
                for (int j = 0; j < 8; ++j) {
                    union { float4 f4; __half2 h2[4]; } hh;
                    hh.f4 = hv4[fq * 8 + j];
#pragma unroll
                    for (int k2 = 0; k2 < 4; ++k2)
                        fa = dot2f(wfc[j * 4 + k2], hh.h2[k2], fa);
                }
                fa += __shfl_xor(fa, 1, 64);
                fa += __shfl_xor(fa, 2, 64);
                if (fq == 0) out[(size_t)(t - 1) * 64 + fo] = fa + bfc;
            }
        }
        __syncthreads();
    }

    if (u >= 0 && u < 256) {
        const float4* hv4 = reinterpret_cast<const float4*>(hl2[1]);
        float fa = 0.f;
#pragma unroll
        for (int j = 0; j < 8; ++j) {
            union { float4 f4; __half2 h2[4]; } hh;
            hh.f4 = hv4[fq * 8 + j];
#pragma unroll
            for (int k2 = 0; k2 < 4; ++k2)
                fa = dot2f(wfc[j * 4 + k2], hh.h2[k2], fa);
        }
        fa += __shfl_xor(fa, 1, 64);
        fa += __shfl_xor(fa, 2, 64);
        if (fq == 0) out[(size_t)(T_LEN - 1) * 64 + fo] = fa + bfc;
    }
}

extern "C" void kernel_launch(void* const* d_in, const int* in_sizes, int n_in,
                              void* d_out, int out_size, void* d_ws, size_t ws_size,
                              hipStream_t stream)
{
    const float* x    = (const float*)d_in[0];
    const float* W_ih = (const float*)d_in[1];
    const float* W_hh = (const float*)d_in[2];
    const float* b_ih = (const float*)d_in[3];
    const float* b_hh = (const float*)d_in[4];
    const float* W_fc = (const float*)d_in[5];
    const float* b_fc = (const float*)d_in[6];
    float* out = (float*)d_out;

    const size_t GX_BYTES = (size_t)TC * G3 * sizeof(float);    // 25.2 MB
    const size_t HS_BYTES = (size_t)TC * HID * sizeof(__half);  //  4.2 MB
    const size_t ST_BYTES = (size_t)HID * sizeof(float);        //  1 KB
    const int NCHUNK = T_LEN / TC;                              // 16

    if (ws_size >= GX_BYTES + HS_BYTES + ST_BYTES) {
        float*  gxb    = (float*)d_ws;
        __half* hsb    = (__half*)((char*)d_ws + GX_BYTES);
        float*  hstate = (float*)((char*)d_ws + GX_BYTES + HS_BYTES);
        for (int c = 0; c < NCHUNK; ++c) {
            const size_t tb = (size_t)c * TC;
            gx_kernel<<<dim3(TC / 64, G3 / 64), dim3(256), 0, stream>>>(
                x + tb * 64, W_ih, b_ih, b_hh, gxb);
            scan_chunk<<<dim3(1), dim3(768), 0, stream>>>(
                gxb, W_hh, b_hh, hsb, hstate, c == 0 ? 1 : 0);
            fc_kernel<<<dim3(TC / 64), dim3(256), 0, stream>>>(
                hsb, W_fc, b_fc, out + tb * 64);
        }
    } else {
        gru_fused<<<dim3(1), dim3(768), 0, stream>>>(x, W_ih, W_hh, b_ih, b_hh, W_fc, b_fc, out);
    }
}